// Round 6
// baseline (196.908 us; speedup 1.0000x reference)
//
#include <hip/hip_runtime.h>

#define LN_EPS 1e-5f
#define LOG2E 1.44269504f
#define NHALF_LOG2E (-0.72134752f)

#if __has_builtin(__builtin_amdgcn_exp2f)
#define EXP2F(x) __builtin_amdgcn_exp2f(x)
#else
#define EXP2F(x) __expf((x) * 0.69314718f)
#endif

typedef float v2f __attribute__((ext_vector_type(2)));

// ---------------------------------------------------------------------------
// Transpose x (32 x KIN) -> xT (KIN x 32). idx = i*32 + b; writes coalesced.
// ---------------------------------------------------------------------------
template<int KIN>
__global__ __launch_bounds__(256)
void transpose_x(const float* __restrict__ x, float* __restrict__ xT)
{
    int idx = blockIdx.x * 256 + threadIdx.x;
    int i = idx >> 5, b = idx & 31;
    xT[idx] = x[b * KIN + i];
}

// ---------------------------------------------------------------------------
// Wavelet linear, multi-output per wave. Wave owns NO consecutive o's and
// i-range [si*RANGE, (si+1)*RANGE). Lane = (p=batch-pair, g=i-subgroup).
// Phase 1: prep {inv, -t*inv, w} for NO*RANGE (o,i) pairs into LDS.
// Phase 2: load x slice ONCE into registers (STEPS x float2 = RANGE/2 VGPRs),
//   then loop o: read prep via same-address LDS broadcast (free), accumulate,
//   reduce (2 shuffles), store. x L2 traffic divided by NO vs one-o-per-wave.
// Per-o acc is reduced+stored immediately -> only 1 live acc pair.
// ---------------------------------------------------------------------------
template<int KIN, int S, int NO>
__global__ __launch_bounds__(128, 4)
void wav_layer(const float* __restrict__ xT, const float* __restrict__ w,
               const float* __restrict__ t, const float* __restrict__ s,
               float* __restrict__ part)
{
    constexpr int RANGE = KIN / S;     // i-values per wave
    constexpr int STEPS = RANGE / 4;
    __shared__ float2 prepA[2][NO][RANGE];  // {inv, -t*inv}
    __shared__ float  prepW[2][NO][RANGE];  // w

    const int wave  = threadIdx.x >> 6;
    const int lane  = threadIdx.x & 63;
    const int obase = ((blockIdx.x << 1) + wave) * NO;
    const int si    = blockIdx.y;
    const int ibase = si * RANGE;

#pragma unroll
    for (int e = lane; e < NO * RANGE; e += 64) {
        int ol = e / RANGE, il = e - ol * RANGE;
        size_t gi = (size_t)(obase + ol) * KIN + ibase + il;
        float wv = w[gi], tv = t[gi], sv = s[gi];
        float sig = __builtin_amdgcn_rcpf(1.f + EXP2F(-sv * LOG2E));
        float inv = __builtin_amdgcn_rcpf(fmaf(9.99f, sig, 0.01000001f));
        prepA[wave][ol][il] = make_float2(inv, -tv * inv);
        prepW[wave][ol][il] = wv;
    }
    __syncthreads();

    const int p = lane & 15, g = lane >> 4;
    const v2f* __restrict__ xp = (const v2f*)xT + (size_t)(ibase + g) * 16 + p;

    v2f xr[STEPS];
#pragma unroll
    for (int st = 0; st < STEPS; ++st) xr[st] = xp[(size_t)st * 64];

#pragma unroll
    for (int ol = 0; ol < NO; ++ol) {
        v2f acc = {0.f, 0.f};
#pragma unroll
        for (int st = 0; st < STEPS; ++st) {
            float2 pr = prepA[wave][ol][st * 4 + g];
            float  wj = prepW[wave][ol][st * 4 + g];
            v2f u  = __builtin_elementwise_fma(xr[st], (v2f){pr.x, pr.x},
                                               (v2f){pr.y, pr.y});
            v2f q  = u * u;
            v2f ev = {EXP2F(q.x * NHALF_LOG2E), EXP2F(q.y * NHALF_LOG2E)};
            v2f pw = __builtin_elementwise_fma((v2f){-wj, -wj}, q,
                                               (v2f){wj, wj});   // w*(1-q)
            acc = __builtin_elementwise_fma(pw, ev, acc);
        }
        float a0 = acc.x, a1 = acc.y;
        a0 += __shfl_down(a0, 32); a0 += __shfl_down(a0, 16);
        a1 += __shfl_down(a1, 32); a1 += __shfl_down(a1, 16);
        if (lane < 16) {
            float2* pp = (float2*)(part + (size_t)si * 16384 + (obase + ol) * 32) + p;
            *pp = make_float2(a0, a1);
        }
    }
}

// ---------------------------------------------------------------------------
// Sum S partial slices (part layout [si][o][b]) + silu + LayerNorm(512).
// Block = batch row b, tid = o. Writes hT[o][b] (input layout for next wav).
// ---------------------------------------------------------------------------
template<int S>
__global__ __launch_bounds__(512)
void silu_ln(const float* __restrict__ part, const float* __restrict__ g,
             const float* __restrict__ bias, float* __restrict__ hT)
{
    const int b = blockIdx.x, tid = threadIdx.x;
    float v = 0.f;
#pragma unroll
    for (int si = 0; si < S; ++si) v += part[(size_t)si * 16384 + tid * 32 + b];
    float a = v * __builtin_amdgcn_rcpf(1.f + EXP2F(-v * LOG2E));  // silu

    float s1 = a, s2 = a * a;
#pragma unroll
    for (int off = 32; off; off >>= 1) {
        s1 += __shfl_down(s1, off);
        s2 += __shfl_down(s2, off);
    }
    __shared__ float r1[8], r2[8];
    const int lane = tid & 63, wid = tid >> 6;
    if (lane == 0) { r1[wid] = s1; r2[wid] = s2; }
    __syncthreads();
    float t1 = 0.f, t2 = 0.f;
#pragma unroll
    for (int k = 0; k < 8; ++k) { t1 += r1[k]; t2 += r2[k]; }
    float m   = t1 * (1.f / 512.f);
    float var = t2 * (1.f / 512.f) - m * m;
    float r   = __builtin_amdgcn_rsqf(var + LN_EPS);
    hT[tid * 32 + b] = (a - m) * r * g[tid] + bias[tid];
}

// ---------------------------------------------------------------------------
// Final: sum partials + silu + LN + classifier (out = hln @ cw.T + cb).
// ---------------------------------------------------------------------------
template<int S>
__global__ __launch_bounds__(512)
void silu_ln_cls(const float* __restrict__ part, const float* __restrict__ g,
                 const float* __restrict__ bias, const float* __restrict__ cw,
                 const float* __restrict__ cb, float* __restrict__ out)
{
    const int b = blockIdx.x, tid = threadIdx.x;
    float v = 0.f;
#pragma unroll
    for (int si = 0; si < S; ++si) v += part[(size_t)si * 16384 + tid * 32 + b];
    float a = v * __builtin_amdgcn_rcpf(1.f + EXP2F(-v * LOG2E));

    float s1 = a, s2 = a * a;
#pragma unroll
    for (int off = 32; off; off >>= 1) {
        s1 += __shfl_down(s1, off);
        s2 += __shfl_down(s2, off);
    }
    __shared__ float r1[8], r2[8];
    const int lane = tid & 63, wid = tid >> 6;
    if (lane == 0) { r1[wid] = s1; r2[wid] = s2; }
    __syncthreads();
    float t1 = 0.f, t2 = 0.f;
#pragma unroll
    for (int k = 0; k < 8; ++k) { t1 += r1[k]; t2 += r2[k]; }
    float m   = t1 * (1.f / 512.f);
    float var = t2 * (1.f / 512.f) - m * m;
    float r   = __builtin_amdgcn_rsqf(var + LN_EPS);
    float hl  = (a - m) * r * g[tid] + bias[tid];

    __shared__ float cr[5][8];
#pragma unroll
    for (int c = 0; c < 5; ++c) {
        float pv = hl * cw[c * 512 + tid];
#pragma unroll
        for (int off = 32; off; off >>= 1) pv += __shfl_down(pv, off);
        if (lane == 0) cr[c][wid] = pv;
    }
    __syncthreads();
    if (tid < 5) {
        float sum = 0.f;
#pragma unroll
        for (int k = 0; k < 8; ++k) sum += cr[tid][k];
        out[b * 5 + tid] = sum + cb[tid];
    }
}

extern "C" void kernel_launch(void* const* d_in, const int* in_sizes, int n_in,
                              void* d_out, int out_size, void* d_ws, size_t ws_size,
                              hipStream_t stream)
{
    const float* x  = (const float*)d_in[0];
    const float* w0 = (const float*)d_in[1];
    const float* t0 = (const float*)d_in[2];
    const float* s0 = (const float*)d_in[3];
    const float* g0 = (const float*)d_in[4];
    const float* b0 = (const float*)d_in[5];
    const float* w1 = (const float*)d_in[6];
    const float* t1 = (const float*)d_in[7];
    const float* s1 = (const float*)d_in[8];
    const float* g1 = (const float*)d_in[9];
    const float* b1 = (const float*)d_in[10];
    const float* w2 = (const float*)d_in[11];
    const float* t2 = (const float*)d_in[12];
    const float* s2 = (const float*)d_in[13];
    const float* g2 = (const float*)d_in[14];
    const float* b2 = (const float*)d_in[15];
    const float* cw = (const float*)d_in[16];
    const float* cb = (const float*)d_in[17];
    float* out = (float*)d_out;

    // ws layout (floats): xT 196608 | part 64*16384 | hT 16384 (~5 MB)
    float* xT   = (float*)d_ws;
    float* part = xT + 196608;
    float* hT   = part + 64 * 16384;

    transpose_x<6144><<<768, 256, 0, stream>>>(x, xT);
    // layer 0: NO=8 o/wave, S=64 -> RANGE=96, grid 32x64=2048 blocks
    wav_layer<6144, 64, 8><<<dim3(32, 64), 128, 0, stream>>>(xT, w0, t0, s0, part);
    silu_ln<64><<<32, 512, 0, stream>>>(part, g0, b0, hT);
    // layers 1-2: NO=4, S=16 -> RANGE=32, grid 64x16=1024 blocks
    wav_layer<512, 16, 4><<<dim3(64, 16), 128, 0, stream>>>(hT, w1, t1, s1, part);
    silu_ln<16><<<32, 512, 0, stream>>>(part, g1, b1, hT);
    wav_layer<512, 16, 4><<<dim3(64, 16), 128, 0, stream>>>(hT, w2, t2, s2, part);
    silu_ln_cls<16><<<32, 512, 0, stream>>>(part, g2, b2, cw, cb, out);
}

// Round 7
// 172.901 us; speedup vs baseline: 1.1389x; 1.1389x over previous
//
#include <hip/hip_runtime.h>

#define LN_EPS 1e-5f
#define LOG2E 1.44269504f
#define NHALF_LOG2E (-0.72134752f)

#if __has_builtin(__builtin_amdgcn_exp2f)
#define EXP2F(x) __builtin_amdgcn_exp2f(x)
#else
#define EXP2F(x) __expf((x) * 0.69314718f)
#endif

typedef float v2f __attribute__((ext_vector_type(2)));

// ---------------------------------------------------------------------------
// Transpose x (32 x KIN) -> xT (KIN x 32). idx = i*32 + b; writes coalesced.
// ---------------------------------------------------------------------------
template<int KIN>
__global__ __launch_bounds__(256)
void transpose_x(const float* __restrict__ x, float* __restrict__ xT)
{
    int idx = blockIdx.x * 256 + threadIdx.x;
    int i = idx >> 5, b = idx & 31;
    xT[idx] = x[b * KIN + i];
}

// ---------------------------------------------------------------------------
// Wavelet linear, NO outputs per wave, x staged in registers.
// Wave owns o in [obase, obase+NO), i in [si*RANGE, (si+1)*RANGE).
// Lane = (p = lane&15 -> batches 2p,2p+1 ; g = lane>>4 -> i-subgroup).
// Phase 1: prep {inv, -t*inv, w} for NO*RANGE (o,i) pairs into LDS.
// Phase 2: x slice loaded ONCE (STEPS v2f regs), loop over o reading prep via
//   same-address LDS broadcast; per-o result reduced (2 shuffles) into
//   res[ol] held by lanes 0..15.
// Epilogue: lane p owns NO consecutive-o results for batches 2p, 2p+1 ->
//   2*NO/4 dwordx4 stores into part[si][b][o] (consecutive o contiguous).
// part layout [si][b][o] makes the downstream sum fully coalesced.
// ---------------------------------------------------------------------------
template<int KIN, int S, int NO>
__global__ __launch_bounds__(128, 4)
void wav_layer(const float* __restrict__ xT, const float* __restrict__ w,
               const float* __restrict__ t, const float* __restrict__ s,
               float* __restrict__ part)
{
    constexpr int RANGE = KIN / S;     // i-values per wave
    constexpr int STEPS = RANGE / 4;
    __shared__ float2 prepA[2][NO][RANGE];  // {inv, -t*inv}
    __shared__ float  prepW[2][NO][RANGE];  // w

    const int wave  = threadIdx.x >> 6;
    const int lane  = threadIdx.x & 63;
    const int obase = ((blockIdx.x << 1) + wave) * NO;
    const int si    = blockIdx.y;
    const int ibase = si * RANGE;

#pragma unroll
    for (int e = lane; e < NO * RANGE; e += 64) {
        int ol = e / RANGE, il = e - ol * RANGE;
        size_t gi = (size_t)(obase + ol) * KIN + ibase + il;
        float wv = w[gi], tv = t[gi], sv = s[gi];
        float sig = __builtin_amdgcn_rcpf(1.f + EXP2F(-sv * LOG2E));
        float inv = __builtin_amdgcn_rcpf(fmaf(9.99f, sig, 0.01000001f));
        prepA[wave][ol][il] = make_float2(inv, -tv * inv);
        prepW[wave][ol][il] = wv;
    }
    __syncthreads();

    const int p = lane & 15, g = lane >> 4;
    const v2f* __restrict__ xp = (const v2f*)xT + (size_t)(ibase + g) * 16 + p;

    v2f xr[STEPS];
#pragma unroll
    for (int st = 0; st < STEPS; ++st) xr[st] = xp[(size_t)st * 64];

    float res0[NO], res1[NO];
#pragma unroll
    for (int ol = 0; ol < NO; ++ol) {
        v2f acc = {0.f, 0.f};
#pragma unroll
        for (int st = 0; st < STEPS; ++st) {
            float2 pr = prepA[wave][ol][st * 4 + g];
            float  wj = prepW[wave][ol][st * 4 + g];
            v2f u  = __builtin_elementwise_fma(xr[st], (v2f){pr.x, pr.x},
                                               (v2f){pr.y, pr.y});
            v2f q  = u * u;
            v2f ev = {EXP2F(q.x * NHALF_LOG2E), EXP2F(q.y * NHALF_LOG2E)};
            v2f pw = __builtin_elementwise_fma((v2f){-wj, -wj}, q,
                                               (v2f){wj, wj});   // w*(1-q)
            acc = __builtin_elementwise_fma(pw, ev, acc);
        }
        float a0 = acc.x, a1 = acc.y;
        a0 += __shfl_down(a0, 32); a0 += __shfl_down(a0, 16);
        a1 += __shfl_down(a1, 32); a1 += __shfl_down(a1, 16);
        res0[ol] = a0;  // valid on lanes 0..15 (= batches 2p, 2p+1)
        res1[ol] = a1;
    }

    if (lane < 16) {
        float* base = part + (size_t)si * 16384 + obase;
        float* b0p  = base + (2 * p) * 512;
        float* b1p  = base + (2 * p + 1) * 512;
#pragma unroll
        for (int v = 0; v < NO / 4; ++v) {
            *(float4*)(b0p + 4 * v) = make_float4(res0[4*v], res0[4*v+1],
                                                  res0[4*v+2], res0[4*v+3]);
            *(float4*)(b1p + 4 * v) = make_float4(res1[4*v], res1[4*v+1],
                                                  res1[4*v+2], res1[4*v+3]);
        }
    }
}

// ---------------------------------------------------------------------------
// Sum S partial slices (part layout [si][b][o]; coalesced in tid=o) + silu +
// LayerNorm(512). Block = batch row b. Writes hT[o][b] for the next layer.
// ---------------------------------------------------------------------------
template<int S>
__global__ __launch_bounds__(512)
void silu_ln(const float* __restrict__ part, const float* __restrict__ g,
             const float* __restrict__ bias, float* __restrict__ hT)
{
    const int b = blockIdx.x, tid = threadIdx.x;
    float v = 0.f;
#pragma unroll
    for (int si = 0; si < S; ++si) v += part[(size_t)si * 16384 + b * 512 + tid];
    float a = v * __builtin_amdgcn_rcpf(1.f + EXP2F(-v * LOG2E));  // silu

    float s1 = a, s2 = a * a;
#pragma unroll
    for (int off = 32; off; off >>= 1) {
        s1 += __shfl_down(s1, off);
        s2 += __shfl_down(s2, off);
    }
    __shared__ float r1[8], r2[8];
    const int lane = tid & 63, wid = tid >> 6;
    if (lane == 0) { r1[wid] = s1; r2[wid] = s2; }
    __syncthreads();
    float t1 = 0.f, t2 = 0.f;
#pragma unroll
    for (int k = 0; k < 8; ++k) { t1 += r1[k]; t2 += r2[k]; }
    float m   = t1 * (1.f / 512.f);
    float var = t2 * (1.f / 512.f) - m * m;
    float r   = __builtin_amdgcn_rsqf(var + LN_EPS);
    hT[tid * 32 + b] = (a - m) * r * g[tid] + bias[tid];
}

// ---------------------------------------------------------------------------
// Final: sum partials + silu + LN + classifier (out = hln @ cw.T + cb).
// ---------------------------------------------------------------------------
template<int S>
__global__ __launch_bounds__(512)
void silu_ln_cls(const float* __restrict__ part, const float* __restrict__ g,
                 const float* __restrict__ bias, const float* __restrict__ cw,
                 const float* __restrict__ cb, float* __restrict__ out)
{
    const int b = blockIdx.x, tid = threadIdx.x;
    float v = 0.f;
#pragma unroll
    for (int si = 0; si < S; ++si) v += part[(size_t)si * 16384 + b * 512 + tid];
    float a = v * __builtin_amdgcn_rcpf(1.f + EXP2F(-v * LOG2E));

    float s1 = a, s2 = a * a;
#pragma unroll
    for (int off = 32; off; off >>= 1) {
        s1 += __shfl_down(s1, off);
        s2 += __shfl_down(s2, off);
    }
    __shared__ float r1[8], r2[8];
    const int lane = tid & 63, wid = tid >> 6;
    if (lane == 0) { r1[wid] = s1; r2[wid] = s2; }
    __syncthreads();
    float t1 = 0.f, t2 = 0.f;
#pragma unroll
    for (int k = 0; k < 8; ++k) { t1 += r1[k]; t2 += r2[k]; }
    float m   = t1 * (1.f / 512.f);
    float var = t2 * (1.f / 512.f) - m * m;
    float r   = __builtin_amdgcn_rsqf(var + LN_EPS);
    float hl  = (a - m) * r * g[tid] + bias[tid];

    __shared__ float cr[5][8];
#pragma unroll
    for (int c = 0; c < 5; ++c) {
        float pv = hl * cw[c * 512 + tid];
#pragma unroll
        for (int off = 32; off; off >>= 1) pv += __shfl_down(pv, off);
        if (lane == 0) cr[c][wid] = pv;
    }
    __syncthreads();
    if (tid < 5) {
        float sum = 0.f;
#pragma unroll
        for (int k = 0; k < 8; ++k) sum += cr[tid][k];
        out[b * 5 + tid] = sum + cb[tid];
    }
}

extern "C" void kernel_launch(void* const* d_in, const int* in_sizes, int n_in,
                              void* d_out, int out_size, void* d_ws, size_t ws_size,
                              hipStream_t stream)
{
    const float* x  = (const float*)d_in[0];
    const float* w0 = (const float*)d_in[1];
    const float* t0 = (const float*)d_in[2];
    const float* s0 = (const float*)d_in[3];
    const float* g0 = (const float*)d_in[4];
    const float* b0 = (const float*)d_in[5];
    const float* w1 = (const float*)d_in[6];
    const float* t1 = (const float*)d_in[7];
    const float* s1 = (const float*)d_in[8];
    const float* g1 = (const float*)d_in[9];
    const float* b1 = (const float*)d_in[10];
    const float* w2 = (const float*)d_in[11];
    const float* t2 = (const float*)d_in[12];
    const float* s2 = (const float*)d_in[13];
    const float* g2 = (const float*)d_in[14];
    const float* b2 = (const float*)d_in[15];
    const float* cw = (const float*)d_in[16];
    const float* cb = (const float*)d_in[17];
    float* out = (float*)d_out;

    // ws layout (floats): xT 196608 | part 64*16384 | hT 16384 (~5 MB)
    float* xT   = (float*)d_ws;
    float* part = xT + 196608;
    float* hT   = part + 64 * 16384;

    transpose_x<6144><<<768, 256, 0, stream>>>(x, xT);
    // layer 0: NO=8 o/wave, S=64 -> RANGE=96, grid 32x64 = 2048 blocks
    wav_layer<6144, 64, 8><<<dim3(32, 64), 128, 0, stream>>>(xT, w0, t0, s0, part);
    silu_ln<64><<<32, 512, 0, stream>>>(part, g0, b0, hT);
    // layers 1-2: NO=4, S=16 -> RANGE=32, grid 64x16 = 1024 blocks
    wav_layer<512, 16, 4><<<dim3(64, 16), 128, 0, stream>>>(hT, w1, t1, s1, part);
    silu_ln<16><<<32, 512, 0, stream>>>(part, g1, b1, hT);
    wav_layer<512, 16, 4><<<dim3(64, 16), 128, 0, stream>>>(hT, w2, t2, s2, part);
    silu_ln_cls<16><<<32, 512, 0, stream>>>(part, g2, b2, cw, cb, out);
}